// Round 10
// baseline (33.666 us; speedup 1.0000x reference)
//
#include <hip/hip_runtime.h>
#include <math.h>

// Problem constants (match reference setup_inputs)
constexpr int B = 32;
constexpr int C = 1024;
constexpr int T = 1024;
constexpr int N = 3;
constexpr int BLK = 1024;  // 16 waves/block
constexpr int CPB = 64;    // channels per block -> grid = 32*16 = 512 = 2/CU
constexpr int CPW = 4;     // channels per wave (16 waves x 4 = 64)

typedef float f4 __attribute__((ext_vector_type(4)));

__device__ __forceinline__ float dot4(const f4 a, const f4 b) {
  return a.x * b.x + a.y * b.y + a.z * b.z + a.w * b.w;
}

// fast tanh via hardware v_exp_f32: tanh(x) = 1 - 2/(e^{2x}+1)
__device__ __forceinline__ float fast_tanh(float x) {
  const float e = __expf(2.0f * x);
  return 1.0f - 2.0f / (e + 1.0f);
}

// ---------------------------------------------------------------------------
// Round 10 = R9 (27.0 us) with the same single lever doubled again:
// BLK 512->1024, CPB 32->64, grid 1024->512 (exactly 2 blocks/CU).
//   * per-CU redundant weight prologues: 4 -> 2 (and each thread now
//     evaluates exactly ONE t-position: 1024 threads cover T=1024)
//   * launch ramp halves again
//   * occupancy ceiling unchanged: 2 blocks x 16 waves = 32 waves/CU
// The load-bearing R2 per-channel loop {16-load burst -> 48 FMA ->
// 18-shfl tail -> store} is untouched (R5-R7: every restructure of it
// regressed ~6 us). Kept: fast __expf prologue, deferred normalization,
// half-row prefetch of channel 0.
// ---------------------------------------------------------------------------
__global__ __launch_bounds__(BLK) void tsf_fused(
    const float* __restrict__ v /* [B][C][T] */,
    const int* __restrict__ length,
    const float* __restrict__ center,
    const float* __restrict__ gamma_,
    float* __restrict__ out /* [B][C][N] */) {
  const int groups_per_b = C / CPB;  // 16
  const int b = blockIdx.x / groups_per_b;
  const int cg = blockIdx.x % groups_per_b;
  const int lane = threadIdx.x & 63;
  const int wv = threadIdx.x >> 6;  // 0..15

  __shared__ float fs[N][T];  // UNNORMALIZED u = 1/(1+d^2), 12 KB
  __shared__ float wsumS[N][BLK / 64];

  const int ch0 = cg * CPB + wv * CPW;
  const f4* r0 = (const f4*)(v + ((size_t)b * C + ch0) * T);

  // ---- prefetch first half of this wave's first row (8 regs) ----
  f4 x0 = r0[lane];
  f4 x1 = r0[lane + 64];

  // ---- prologue: unnormalized weights straight to LDS ----
  // 1024 threads cover T=1024 in one stride.
  const float lf = (float)length[b];
  float scale[N];  // pref, later overwritten with final scale
#pragma unroll
  for (int n = 0; n < N; ++n) {
    const float c = fast_tanh(center[n]);
    const float g = fast_tanh(gamma_[n]);
    const float ctr = (lf - 1.0f) * (c + 1.0f) * 0.5f;
    const float gam = __expf(1.5f - 2.0f * fabsf(g));
    const float inv_gam = 1.0f / gam;
    scale[n] = 1.0f / (3.14159265358979f * gam);  // pref

    const float t = (float)threadIdx.x;
    const float d = (t - ctr) * inv_gam;
    float s = 1.0f / fmaf(d, d, 1.0f);
    fs[n][threadIdx.x] = s;
#pragma unroll
    for (int off = 32; off > 0; off >>= 1) s += __shfl_down(s, off);
    if (lane == 0) wsumS[n][wv] = s;
  }
  __syncthreads();

  // scale[n] = pref / (pref * sum_u + 1e-6)
#pragma unroll
  for (int n = 0; n < N; ++n) {
    float s = 0.0f;
#pragma unroll
    for (int k = 0; k < BLK / 64; ++k) s += wsumS[n][k];
    scale[n] = scale[n] / fmaf(scale[n], s, 1e-6f);
  }

  const f4* w0 = (const f4*)(&fs[0][0]);
  const f4* w1 = (const f4*)(&fs[1][0]);
  const f4* w2 = (const f4*)(&fs[2][0]);

  // ---- peeled channel 0: second half loads now, then consume ----
  {
    const f4 x2 = r0[lane + 128];
    const f4 x3 = r0[lane + 192];

    float a0 = dot4(x0, w0[lane]) + dot4(x1, w0[lane + 64]) +
               dot4(x2, w0[lane + 128]) + dot4(x3, w0[lane + 192]);
    float a1 = dot4(x0, w1[lane]) + dot4(x1, w1[lane + 64]) +
               dot4(x2, w1[lane + 128]) + dot4(x3, w1[lane + 192]);
    float a2 = dot4(x0, w2[lane]) + dot4(x1, w2[lane + 64]) +
               dot4(x2, w2[lane + 128]) + dot4(x3, w2[lane + 192]);

#pragma unroll
    for (int off = 32; off > 0; off >>= 1) {
      a0 += __shfl_down(a0, off);
      a1 += __shfl_down(a1, off);
      a2 += __shfl_down(a2, off);
    }
    if (lane == 0) {
      float* o = out + ((size_t)b * C + ch0) * N;
      o[0] = a0 * scale[0];
      o[1] = a1 * scale[1];
      o[2] = a2 * scale[2];
    }
  }

  // ---- channels 1..3: the load-bearing R2 per-channel loop ----
  for (int cc = 1; cc < CPW; ++cc) {
    const int ch = ch0 + cc;
    const f4* row = (const f4*)(v + ((size_t)b * C + ch) * T);

    float a0 = 0.f, a1 = 0.f, a2 = 0.f;
#pragma unroll
    for (int i = lane; i < T / 4; i += 64) {
      const f4 x = row[i];
      a0 += dot4(x, w0[i]);
      a1 += dot4(x, w1[i]);
      a2 += dot4(x, w2[i]);
    }

#pragma unroll
    for (int off = 32; off > 0; off >>= 1) {
      a0 += __shfl_down(a0, off);
      a1 += __shfl_down(a1, off);
      a2 += __shfl_down(a2, off);
    }

    if (lane == 0) {
      float* o = out + ((size_t)b * C + ch) * N;
      o[0] = a0 * scale[0];
      o[1] = a1 * scale[1];
      o[2] = a2 * scale[2];
    }
  }
}

// ---------------------------------------------------------------------------
extern "C" void kernel_launch(void* const* d_in, const int* in_sizes, int n_in,
                              void* d_out, int out_size, void* d_ws,
                              size_t ws_size, hipStream_t stream) {
  const float* video = (const float*)d_in[0];   // (B, C, T, 1, 1) fp32
  const int* length = (const int*)d_in[1];      // (B,) int32
  const float* center = (const float*)d_in[2];  // (N,) fp32
  // d_in[3] = delta (unused by reference)
  const float* gamma_ = (const float*)d_in[4];  // (N,) fp32
  float* out = (float*)d_out;                   // (B, C*N) fp32

  tsf_fused<<<B * (C / CPB), BLK, 0, stream>>>(video, length, center, gamma_,
                                               out);
}

// Round 11
// 26.955 us; speedup vs baseline: 1.2490x; 1.2490x over previous
//
#include <hip/hip_runtime.h>
#include <math.h>

// Problem constants (match reference setup_inputs)
constexpr int B = 32;
constexpr int C = 1024;
constexpr int T = 1024;
constexpr int N = 3;
constexpr int BLK = 512;  // 8 waves/block (R9 optimum; 1024 regressed in R10)
constexpr int CPB = 32;   // channels per block -> grid = 32*32 = 1024 = 4/CU
constexpr int CPW = 4;    // channels per wave

typedef float f4 __attribute__((ext_vector_type(4)));

__device__ __forceinline__ float dot4(const f4 a, const f4 b) {
  return a.x * b.x + a.y * b.y + a.z * b.z + a.w * b.w;
}

// fast tanh via hardware v_exp_f32: tanh(x) = 1 - 2/(e^{2x}+1)
__device__ __forceinline__ float fast_tanh(float x) {
  const float e = __expf(2.0f * x);
  return 1.0f - 2.0f / (e + 1.0f);
}

// ---------------------------------------------------------------------------
// DPP-based wave64 sum: canonical GCN sequence (row_shr:1/2/4/8 then
// row_bcast:15/31). Runs entirely on the VALU pipe (v_mov_dpp + v_add),
// ~2-4 cyc/step, vs __shfl_down's ds_bpermute chains on the DS pipe
// (~30 cyc dependent latency each, and they contend with the ds_read_b128
// weight reads). Result valid in LANE 63 only.
// ---------------------------------------------------------------------------
__device__ __forceinline__ float wred_dpp(float x) {
#define DPP_ADD(ctrl)                                                        \
  x += __int_as_float(__builtin_amdgcn_update_dpp(                           \
      0, __float_as_int(x), (ctrl), 0xF, 0xF, false));
  DPP_ADD(0x111)  // row_shr:1
  DPP_ADD(0x112)  // row_shr:2
  DPP_ADD(0x114)  // row_shr:4
  DPP_ADD(0x118)  // row_shr:8   -> lane 15 of each 16-row = row sum
  DPP_ADD(0x142)  // row_bcast:15 -> lane31 = rows0+1, lane63 = rows2+3
  DPP_ADD(0x143)  // row_bcast:31 -> lane63 = total
#undef DPP_ADD
  return x;  // lane 63 holds the full 64-lane sum
}

// ---------------------------------------------------------------------------
// Round 11 = R9 (best, 27.0 us) with ONE change: all __shfl_down reduction
// chains replaced by DPP reductions (VALU pipe), stores by lane 63.
// Everything else identical to R9:
//   * BLK=512, CPB=32, grid=1024 (4 blocks/CU, 32 waves/CU, VGPR<=64)
//   * fast __expf prologue; deferred normalization (unnormalized u -> LDS,
//     scale folded into stores); half-row prefetch of channel 0
//   * the load-bearing R2 per-channel loop untouched
// ---------------------------------------------------------------------------
__global__ __launch_bounds__(BLK) void tsf_fused(
    const float* __restrict__ v /* [B][C][T] */,
    const int* __restrict__ length,
    const float* __restrict__ center,
    const float* __restrict__ gamma_,
    float* __restrict__ out /* [B][C][N] */) {
  const int groups_per_b = C / CPB;  // 32
  const int b = blockIdx.x / groups_per_b;
  const int cg = blockIdx.x % groups_per_b;
  const int lane = threadIdx.x & 63;
  const int wv = threadIdx.x >> 6;  // 0..7

  __shared__ float fs[N][T];  // UNNORMALIZED u = 1/(1+d^2), 12 KB
  __shared__ float wsumS[N][BLK / 64];

  const int ch0 = cg * CPB + wv * CPW;
  const f4* r0 = (const f4*)(v + ((size_t)b * C + ch0) * T);

  // ---- prefetch first half of this wave's first row (8 regs) ----
  f4 x0 = r0[lane];
  f4 x1 = r0[lane + 64];

  // ---- prologue: unnormalized weights straight to LDS ----
  // 512 threads cover T=1024 in 2 strides.
  const float lf = (float)length[b];
  float scale[N];  // pref, later overwritten with final scale
#pragma unroll
  for (int n = 0; n < N; ++n) {
    const float c = fast_tanh(center[n]);
    const float g = fast_tanh(gamma_[n]);
    const float ctr = (lf - 1.0f) * (c + 1.0f) * 0.5f;
    const float gam = __expf(1.5f - 2.0f * fabsf(g));
    const float inv_gam = 1.0f / gam;
    scale[n] = 1.0f / (3.14159265358979f * gam);  // pref

    float s = 0.0f;
#pragma unroll
    for (int i = 0; i < 2; ++i) {
      const float t = (float)(threadIdx.x + i * BLK);
      const float d = (t - ctr) * inv_gam;
      const float u = 1.0f / fmaf(d, d, 1.0f);
      fs[n][threadIdx.x + i * BLK] = u;
      s += u;
    }
    s = wred_dpp(s);
    if (lane == 63) wsumS[n][wv] = s;
  }
  __syncthreads();

  // scale[n] = pref / (pref * sum_u + 1e-6)
#pragma unroll
  for (int n = 0; n < N; ++n) {
    float s = 0.0f;
#pragma unroll
    for (int k = 0; k < BLK / 64; ++k) s += wsumS[n][k];
    scale[n] = scale[n] / fmaf(scale[n], s, 1e-6f);
  }

  const f4* w0 = (const f4*)(&fs[0][0]);
  const f4* w1 = (const f4*)(&fs[1][0]);
  const f4* w2 = (const f4*)(&fs[2][0]);

  // ---- peeled channel 0: second half loads now, then consume ----
  {
    const f4 x2 = r0[lane + 128];
    const f4 x3 = r0[lane + 192];

    float a0 = dot4(x0, w0[lane]) + dot4(x1, w0[lane + 64]) +
               dot4(x2, w0[lane + 128]) + dot4(x3, w0[lane + 192]);
    float a1 = dot4(x0, w1[lane]) + dot4(x1, w1[lane + 64]) +
               dot4(x2, w1[lane + 128]) + dot4(x3, w1[lane + 192]);
    float a2 = dot4(x0, w2[lane]) + dot4(x1, w2[lane + 64]) +
               dot4(x2, w2[lane + 128]) + dot4(x3, w2[lane + 192]);

    a0 = wred_dpp(a0);
    a1 = wred_dpp(a1);
    a2 = wred_dpp(a2);
    if (lane == 63) {
      float* o = out + ((size_t)b * C + ch0) * N;
      o[0] = a0 * scale[0];
      o[1] = a1 * scale[1];
      o[2] = a2 * scale[2];
    }
  }

  // ---- channels 1..3: the load-bearing R2 per-channel loop ----
  for (int cc = 1; cc < CPW; ++cc) {
    const int ch = ch0 + cc;
    const f4* row = (const f4*)(v + ((size_t)b * C + ch) * T);

    float a0 = 0.f, a1 = 0.f, a2 = 0.f;
#pragma unroll
    for (int i = lane; i < T / 4; i += 64) {
      const f4 x = row[i];
      a0 += dot4(x, w0[i]);
      a1 += dot4(x, w1[i]);
      a2 += dot4(x, w2[i]);
    }

    a0 = wred_dpp(a0);
    a1 = wred_dpp(a1);
    a2 = wred_dpp(a2);
    if (lane == 63) {
      float* o = out + ((size_t)b * C + ch) * N;
      o[0] = a0 * scale[0];
      o[1] = a1 * scale[1];
      o[2] = a2 * scale[2];
    }
  }
}

// ---------------------------------------------------------------------------
extern "C" void kernel_launch(void* const* d_in, const int* in_sizes, int n_in,
                              void* d_out, int out_size, void* d_ws,
                              size_t ws_size, hipStream_t stream) {
  const float* video = (const float*)d_in[0];   // (B, C, T, 1, 1) fp32
  const int* length = (const int*)d_in[1];      // (B,) int32
  const float* center = (const float*)d_in[2];  // (N,) fp32
  // d_in[3] = delta (unused by reference)
  const float* gamma_ = (const float*)d_in[4];  // (N,) fp32
  float* out = (float*)d_out;                   // (B, C*N) fp32

  tsf_fused<<<B * (C / CPB), BLK, 0, stream>>>(video, length, center, gamma_,
                                               out);
}